// Round 7
// baseline (294.521 us; speedup 1.0000x reference)
//
#include <hip/hip_runtime.h>

typedef unsigned long long u64;
typedef unsigned int u32;

static constexpr int NF = 17;      // features per point
static constexpr int BCOL = 9;     // beta column
static constexpr int CCOL = 14;    // first ccoord column (17-3)
static constexpr int CONDCAP = 256;   // max condensates (geometry bound ~45 for r=0.7 in unit cube)
static constexpr int REFCAP = 256;    // max refs from resolve
static constexpr int CANDCAP = 4096;  // candidate cap per event (expect ~3.3k at TAU0=0.95)
static constexpr int RPB = 512;    // rows per block in k_filter
static constexpr int FT = 1024;    // threads in k_resolve / k_finish2
static constexpr int KB = 8;       // streaming batch depth (MLP)

#define T_B_F  ((float)0.2)        // matches numpy float32(0.2)
#define R2_F   ((float)(0.7*0.7))  // matches numpy float32 semantics
#define TAU0_F ((float)0.95)       // candidate threshold (correctness does NOT depend on it)

__device__ __forceinline__ u64 kmax(u64 a, u64 b){ return a > b ? a : b; }

__device__ __forceinline__ u64 shfl_down_u64(u64 v, int off){
    u32 lo = (u32)v, hi = (u32)(v >> 32);
    lo = __shfl_down(lo, off, 64);
    hi = __shfl_down(hi, off, 64);
    return ((u64)hi << 32) | lo;
}

__device__ __forceinline__ u64 shfl_u64(u64 v, int lane){
    u32 lo = (u32)v, hi = (u32)(v >> 32);
    lo = __shfl(lo, lane, 64);
    hi = __shfl(hi, lane, 64);
    return ((u64)hi << 32) | lo;
}

__device__ __forceinline__ u64 shfl_xor_u64(u64 v, int mask){
    u32 lo = (u32)v, hi = (u32)(v >> 32);
    lo = __shfl_xor(lo, mask, 64);
    hi = __shfl_xor(hi, mask, 64);
    return ((u64)hi << 32) | lo;
}

__device__ __forceinline__ u64 waveReduceMax(u64 k){
    #pragma unroll
    for (int off = 32; off > 0; off >>= 1){
        u64 o = shfl_down_u64(k, off);
        if (o > k) k = o;
    }
    return k;
}

// distance with NO fp contraction — must match numpy (mul,mul,mul,add,add)
__device__ __forceinline__ float dist2(float cx, float cy, float cz,
                                       float rx, float ry, float rz){
    #pragma clang fp contract(off)
    float dx = cx - rx, dy = cy - ry, dz = cz - rz;
    float sx = dx * dx, sy = dy * dy, sz = dz * dz;
    return (sx + sy) + sz;
}

__device__ __forceinline__ u64 makeKey(float beta, u32 idx){
    return ((u64)__float_as_uint(beta) << 32) | (u64)(0xFFFFFFFFu - idx);
}

// ---------------- kernel 0: zero control block (4 KB) ----------------
__global__ void k_init(u32* ws){
    int t = threadIdx.x;
    if (t < 1024) ws[t] = 0;   // argmax1, cnt0, cnt1, candCnt, nrefs, ncond, done
}

// ---------------- kernel 1: zero dout + filter beta>=T_B + candidate push ----
__global__ __launch_bounds__(512) void k_filter(
    const float4* __restrict__ x4, float4* __restrict__ out4,
    int* __restrict__ cnt0, float4* __restrict__ cA, int* __restrict__ iA,
    int* __restrict__ candCnt, int* __restrict__ candI,
    int P, int chunksPerEvent)
{
    __shared__ float lds[RPB * NF];           // 34816 B
    __shared__ int swc[8], swb[8], sbase;
    __shared__ int swc2[8], swb2[8], sbase2;

    int e = blockIdx.x / chunksPerEvent;
    int chunk = blockIdx.x % chunksPerEvent;
    int rowStart = chunk * RPB;
    size_t tile4 = (size_t)blockIdx.x * (RPB * NF / 4);   // 2176 float4 per tile

    float4* lds4 = (float4*)lds;
    const int N4 = RPB * NF / 4;
    float4 z = make_float4(0.f, 0.f, 0.f, 0.f);
    for (int i = threadIdx.x; i < N4; i += 512){
        lds4[i] = x4[tile4 + i];
        out4[tile4 + i] = z;                   // fused zero of dout
    }
    __syncthreads();

    int tid = threadIdx.x, lid = tid & 63, wid = tid >> 6;
    float be = lds[tid*NF+BCOL];
    float cx = lds[tid*NF+CCOL], cy = lds[tid*NF+CCOL+1], cz = lds[tid*NF+CCOL+2];
    bool kp = (be >= T_B_F);
    bool cd = (be >= TAU0_F);
    u64 bal  = __ballot(kp);
    u64 bal2 = __ballot(cd);
    if (lid == 0){ swc[wid] = __popcll(bal); swc2[wid] = __popcll(bal2); }
    __syncthreads();
    if (tid == 0){
        int tot = 0, tot2 = 0;
        for (int w = 0; w < 8; w++){
            swb[w] = tot;  tot  += swc[w];
            swb2[w] = tot2; tot2 += swc2[w];
        }
        sbase  = tot  ? atomicAdd(&cnt0[e], tot)     : 0;   // 1 returning atomic / block
        sbase2 = tot2 ? atomicAdd(&candCnt[e], tot2) : 0;
    }
    __syncthreads();
    u64 lm = (1ull << lid) - 1;
    if (kp){
        int pos = sbase + swb[wid] + __popcll(bal & lm);
        size_t eoff = (size_t)e * P;
        cA[eoff + pos] = make_float4(cx, cy, cz, be);
        iA[eoff + pos] = rowStart + tid;
    }
    if (cd){
        int pos = sbase2 + swb2[wid] + __popcll(bal2 & lm);
        if (pos < CANDCAP) candI[e * CANDCAP + pos] = rowStart + tid;
    }
}

// ---------------- kernel 2: per-event exact greedy MIS over candidates --------
// Candidate set = ALL filtered points with beta >= TAU0 (complete by construction
// when no overflow), so every accept is exact: kills come only from higher-key
// points, which are all candidates. Sort desc in LDS (bitonic), then wave 0 walks
// chunks of 64: parallel test vs accepted refs, then ballot-walk accepts.
__global__ __launch_bounds__(1024) void k_resolve(
    const float* __restrict__ x, const int* __restrict__ candCnt,
    const int* __restrict__ candI, int* __restrict__ nrefs,
    int* __restrict__ condlist, float* __restrict__ refXg,
    float* __restrict__ refYg, float* __restrict__ refZg, int P)
{
    __shared__ u64 kbuf[CANDCAP];                    // 32 KB
    __shared__ int pbuf[CANDCAP];                    // 16 KB
    __shared__ float ccx[CANDCAP], ccy[CANDCAP], ccz[CANDCAP];   // 48 KB
    __shared__ float rfx[REFCAP], rfy[REFCAP], rfz[REFCAP];
    __shared__ int rci[REFCAP];
    __shared__ int snr;

    int e = blockIdx.x;
    int tid = threadIdx.x, lid = tid & 63, wid = tid >> 6;
    int m = candCnt[e];
    if (m > CANDCAP){ if (tid == 0) nrefs[e] = 0; return; }   // overflow -> full fallback

    int M = 64; while (M < m) M <<= 1;

    for (int i = tid; i < M; i += FT){
        u64 k = 0;
        if (i < m){
            int idx = candI[e * CANDCAP + i];
            size_t rb = ((size_t)e * P + idx) * NF;
            float be = x[rb + BCOL];
            k = makeKey(be, (u32)idx);
            ccx[i] = x[rb + CCOL]; ccy[i] = x[rb + CCOL + 1]; ccz[i] = x[rb + CCOL + 2];
        }
        kbuf[i] = k; pbuf[i] = i;
    }
    __syncthreads();

    // bitonic sort desc by key (pad keys = 0 sort to the end)
    for (int bs = 2; bs <= M; bs <<= 1){
        for (int bj = bs >> 1; bj > 0; bj >>= 1){
            for (int i = tid; i < M; i += FT){
                int j = i ^ bj;
                if (j > i){
                    bool desc = ((i & bs) == 0);
                    u64 a = kbuf[i], b = kbuf[j];
                    if ((a < b) == desc){
                        kbuf[i] = b; kbuf[j] = a;
                        int t = pbuf[i]; pbuf[i] = pbuf[j]; pbuf[j] = t;
                    }
                }
            }
            __syncthreads();
        }
    }

    if (wid == 0){
        int nr = 0;
        for (int c0 = 0; c0 < M; c0 += 64){
            int i = c0 + lid;                  // i < M (M multiple of 64)
            u64 k = kbuf[i];
            bool valid = (k != 0);
            float px = 0.f, py = 0.f, pz = 0.f;
            if (valid){ int p = pbuf[i]; px = ccx[p]; py = ccy[p]; pz = ccz[p]; }
            bool alive = valid;
            for (int r = 0; r < nr; r++){
                if (alive && dist2(px, py, pz, rfx[r], rfy[r], rfz[r]) <= R2_F) alive = false;
            }
            u64 B = __ballot(alive);
            while (B){
                int j = (int)(__ffsll((unsigned long long)B) - 1);   // highest key alive
                float jx = __shfl(px, j, 64), jy = __shfl(py, j, 64), jz = __shfl(pz, j, 64);
                u64 jk = shfl_u64(k, j);
                if (nr < REFCAP){
                    if (lid == 0){
                        rfx[nr] = jx; rfy[nr] = jy; rfz[nr] = jz;
                        rci[nr] = (int)(0xFFFFFFFFu - (u32)jk);
                    }
                    nr++;
                }
                bool kill = alive && (dist2(px, py, pz, jx, jy, jz) <= R2_F);  // j kills itself too
                B &= ~__ballot(kill);
            }
        }
        if (lid == 0) snr = nr;
    }
    __syncthreads();
    int nr = snr;
    for (int i = tid; i < nr; i += FT){
        refXg[e*REFCAP + i] = rfx[i];
        refYg[e*REFCAP + i] = rfy[i];
        refZg[e*REFCAP + i] = rfz[i];
        condlist[e*CONDCAP + i] = rci[i];
    }
    if (tid == 0) nrefs[e] = nr;
}

// ---------------- kernel 3: full-grid kill pass vs all resolved refs ----------
// Survivors (> r from every ref) are compacted to cB/iB; whp there are none.
__global__ __launch_bounds__(256) void k_kill(
    const float4* __restrict__ cA, const int* __restrict__ iA,
    float4* __restrict__ cB, int* __restrict__ iB,
    const int* __restrict__ cnt0, int* __restrict__ cnt1,
    u64* __restrict__ argmax1, const int* __restrict__ nrefs,
    const float* __restrict__ refXg, const float* __restrict__ refYg,
    const float* __restrict__ refZg, int P, int bpe)
{
    __shared__ float rfx[REFCAP], rfy[REFCAP], rfz[REFCAP];
    __shared__ int swc[4], swb[4], sbase;
    __shared__ u64 sred[4];

    int e = blockIdx.x / bpe;
    int c = blockIdx.x % bpe;
    int n = cnt0[e];
    if (c * 256 >= n) return;                  // uniform early-out
    int nr = nrefs[e];
    for (int i = threadIdx.x; i < nr; i += 256){
        rfx[i] = refXg[e*REFCAP + i];
        rfy[i] = refYg[e*REFCAP + i];
        rfz[i] = refZg[e*REFCAP + i];
    }
    __syncthreads();

    int tid = threadIdx.x, lid = tid & 63, wid = tid >> 6;
    size_t eoff = (size_t)e * P;
    int stride = bpe * 256;

    float4 cc[KB]; int ixv[KB]; bool kp[KB]; u64 bal[KB];
    int wcnt = 0; u64 lk = 0;
    #pragma unroll
    for (int k = 0; k < KB; k++){
        int i = c * 256 + tid + k * stride;
        bool inb = i < n;
        int ii = inb ? i : 0;
        cc[k] = cA[eoff + ii]; ixv[k] = iA[eoff + ii];
        bool alive = inb;
        for (int r = 0; r < nr; r++){
            if (alive && dist2(cc[k].x, cc[k].y, cc[k].z, rfx[r], rfy[r], rfz[r]) <= R2_F)
                alive = false;
        }
        kp[k] = alive;
        bal[k] = __ballot(alive);
        wcnt += __popcll(bal[k]);
        if (alive) lk = kmax(lk, makeKey(cc[k].w, (u32)ixv[k]));
    }
    u64 kw = waveReduceMax(lk);
    if (lid == 0){ swc[wid] = wcnt; sred[wid] = kw; }
    __syncthreads();
    if (tid == 0){
        int tot = 0;
        for (int w = 0; w < 4; w++){ swb[w] = tot; tot += swc[w]; }
        sbase = tot ? atomicAdd(&cnt1[e], tot) : 0;
        u64 mm = kmax(kmax(sred[0], sred[1]), kmax(sred[2], sred[3]));
        if (mm) atomicMax(&argmax1[e], mm);
    }
    __syncthreads();
    int pos = sbase + swb[wid];
    u64 lm = (1ull << lid) - 1;
    #pragma unroll
    for (int k = 0; k < KB; k++){
        if (kp[k]){
            int p_ = pos + __popcll(bal[k] & lm);
            cB[eoff + p_] = cc[k]; iB[eoff + p_] = ixv[k];
        }
        pos += __popcll(bal[k]);
    }
}

// ---------------- kernel 4: fallback NMS on survivors (usually 0) + epilogue --
__global__ __launch_bounds__(1024) void k_finish2(
    const float* __restrict__ x,
    float4* cB, int* iB, float4* cA, int* iA,
    const u64* __restrict__ argmax1, const int* __restrict__ cnt1,
    const int* __restrict__ nrefs, int* __restrict__ ncond,
    const int* __restrict__ condlistG, int* __restrict__ done,
    float* __restrict__ out, int P, int E)
{
    __shared__ u64 wtopk[64];
    __shared__ int wtopp[64];
    __shared__ float refX[64], refY[64], refZ[64];
    __shared__ int condL[CONDCAP];
    __shared__ int scnt, snc, snr;

    int e = blockIdx.x;
    int tid = threadIdx.x, lid = tid & 63, wid = tid >> 6;
    int n = cnt1[e];
    u64 key0 = argmax1[e];
    float4* cIn = cB + (size_t)e * P; int* iIn = iB + (size_t)e * P;
    float4* cOut = cA + (size_t)e * P; int* iOut = iA + (size_t)e * P;

    int nr0 = nrefs[e];
    for (int i = tid; i < nr0; i += FT) condL[i] = condlistG[e*CONDCAP + i];
    if (tid == 0){
        snc = nr0; scnt = 0; snr = 0;
        float b0 = __uint_as_float((u32)(key0 >> 32));
        if (n > 0 && b0 >= T_B_F){
            u32 refIdx = 0xFFFFFFFFu - (u32)key0;
            if (nr0 < CONDCAP) condL[nr0] = (int)refIdx;
            snc = nr0 + 1; snr = 1;
            size_t rbase = ((size_t)e * P + refIdx) * NF;
            refX[0] = x[rbase + CCOL];
            refY[0] = x[rbase + CCOL + 1];
            refZ[0] = x[rbase + CCOL + 2];
        }
    }
    __syncthreads();

    while (snr > 0){
        int nr = snr;
        // ---- (a) kill + compact + per-wave top-4 collect ----
        u64 k4a=0,k4b=0,k4c=0,k4d=0; int p4a=0,p4b=0,p4c=0,p4d=0;
        for (int base = 0; base < n; base += FT * KB){
            float4 cc[KB]; int ixv[KB]; bool kp[KB]; u64 bal[KB];
            #pragma unroll
            for (int k = 0; k < KB; k++){
                int i = base + tid + k * FT;
                bool inb = i < n; int ii = inb ? i : 0;
                cc[k] = cIn[ii]; ixv[k] = iIn[ii];
                kp[k] = inb;
            }
            #pragma unroll
            for (int k = 0; k < KB; k++){
                if (kp[k]){
                    for (int r = 0; r < nr; r++){
                        if (dist2(cc[k].x, cc[k].y, cc[k].z,
                                  refX[r], refY[r], refZ[r]) <= R2_F){ kp[k] = false; break; }
                    }
                }
            }
            int wcnt = 0;
            #pragma unroll
            for (int k = 0; k < KB; k++){ bal[k] = __ballot(kp[k]); wcnt += __popcll(bal[k]); }
            int wb = 0;
            if (lid == 0) wb = wcnt ? atomicAdd(&scnt, wcnt) : 0;
            wb = __shfl(wb, 0, 64);
            u64 lm = (1ull << lid) - 1;
            #pragma unroll
            for (int k = 0; k < KB; k++){
                if (kp[k]){
                    int pos = wb + __popcll(bal[k] & lm);
                    cOut[pos] = cc[k]; iOut[pos] = ixv[k];
                    u64 kk = makeKey(cc[k].w, (u32)ixv[k]);
                    if (kk > k4d){
                        if (kk > k4a){ k4d=k4c;p4d=p4c; k4c=k4b;p4c=p4b; k4b=k4a;p4b=p4a; k4a=kk;p4a=pos; }
                        else if (kk > k4b){ k4d=k4c;p4d=p4c; k4c=k4b;p4c=p4b; k4b=kk;p4b=pos; }
                        else if (kk > k4c){ k4d=k4c;p4d=p4c; k4c=kk;p4c=pos; }
                        else { k4d=kk; p4d=pos; }
                    }
                }
                wb += __popcll(bal[k]);
            }
        }
        {   // wave-merge per-lane top4 -> wave top4
            u64 excl = ~0ull;
            #pragma unroll
            for (int j = 0; j < 4; j++){
                u64 lk = 0; int lp = 0;
                if (k4a < excl && k4a > lk){ lk = k4a; lp = p4a; }
                if (k4b < excl && k4b > lk){ lk = k4b; lp = p4b; }
                if (k4c < excl && k4c > lk){ lk = k4c; lp = p4c; }
                if (k4d < excl && k4d > lk){ lk = k4d; lp = p4d; }
                #pragma unroll
                for (int off = 32; off > 0; off >>= 1){
                    u64 ok = shfl_down_u64(lk, off);
                    int op = __shfl_down(lp, off, 64);
                    if (ok > lk){ lk = ok; lp = op; }
                }
                lk = shfl_u64(lk, 0); lp = __shfl(lp, 0, 64);
                if (lid == 0){ wtopk[wid*4 + j] = lk; wtopp[wid*4 + j] = lp; }
                excl = lk;
            }
        }
        __syncthreads();
        n = scnt;
        { float4* t = cIn; cIn = cOut; cOut = t; }
        { int* t = iIn; iIn = iOut; iOut = t; }
        if (n == 0) break;

        // ---- (b) resolve next refs (wave 0 only) ----
        if (wid == 0){
            u64 key = wtopk[lid]; int pos = wtopp[lid];
            u64 tt = (lid < 16) ? wtopk[lid*4 + 3] : 0;
            u64 tau = waveReduceMax(tt); tau = shfl_u64(tau, 0);
            float cx = 0.f, cy = 0.f, cz = 0.f;
            if (key){ float4 c = cIn[pos]; cx = c.x; cy = c.y; cz = c.z; }
            #pragma unroll
            for (int bs = 2; bs <= 64; bs <<= 1){
                #pragma unroll
                for (int bj = bs >> 1; bj > 0; bj >>= 1){
                    u64 ok = shfl_xor_u64(key, bj);
                    float ox = __shfl_xor(cx, bj, 64);
                    float oy = __shfl_xor(cy, bj, 64);
                    float oz = __shfl_xor(cz, bj, 64);
                    bool lower = (lid & bj) == 0;
                    bool segDesc = (lid & bs) == 0;
                    bool takeOther = segDesc ? (lower ? (ok > key) : (ok < key))
                                             : (lower ? (ok < key) : (ok > key));
                    if (takeOther){ key = ok; cx = ox; cy = oy; cz = oz; }
                }
            }
            int killed = (key == 0) ? 1 : 0;
            int nrr = 0;
            int sb = snc;
            for (int j = 0; j < 64; j++){
                u64 kj = shfl_u64(key, j);
                if (kj == 0 || kj <= tau) break;       // completeness boundary
                int kb = __shfl(killed, j, 64);
                if (!kb){
                    float xj = __shfl(cx, j, 64);
                    float yj = __shfl(cy, j, 64);
                    float zj = __shfl(cz, j, 64);
                    if (lid == 0){
                        refX[nrr] = xj; refY[nrr] = yj; refZ[nrr] = zj;
                        int s = sb + nrr;
                        if (s < CONDCAP) condL[s] = (int)(0xFFFFFFFFu - (u32)kj);
                    }
                    nrr++;
                    if (dist2(cx, cy, cz, xj, yj, zj) <= R2_F) killed = 1;
                }
            }
            if (lid == 0){ snr = nrr; snc = sb + nrr; scnt = 0; }
        }
        __syncthreads();
    }
    __syncthreads();

    // ---- epilogue: scatter condensate rows + row_splits (last block) ----
    int ncT = snc;
    int ncc = ncT > CONDCAP ? CONDCAP : ncT;
    for (int i = tid; i < ncc * NF; i += FT){
        int j = i / NF, f = i - j * NF;
        int row = condL[j];
        size_t base = ((size_t)e * P + row) * NF;
        out[base + f] = x[base + f];
    }
    if (tid == 0){
        ncond[e] = ncT;
        __threadfence();
        int r = atomicAdd(done, 1);
        if (r == E - 1){
            size_t ob = (size_t)E * P * NF;
            int s = 0;
            out[ob] = 0.0f;
            for (int i = 0; i < E; i++){
                s += atomicAdd((int*)&ncond[i], 0);   // device-scope read
                out[ob + i + 1] = (float)s;
            }
        }
    }
}

extern "C" void kernel_launch(void* const* d_in, const int* in_sizes, int n_in,
                              void* d_out, int out_size, void* d_ws, size_t ws_size,
                              hipStream_t stream) {
    const float* x = (const float*)d_in[0];
    int N = in_sizes[0] / NF;
    int E = in_sizes[1] - 1;
    int P = N / E;
    float* out = (float*)d_out;
    char* ws = (char*)d_ws;

    // ws layout (first 4 KB zeroed by k_init)
    u64* argmax1 = (u64*)ws;                        // [E]
    int* cnt0    = (int*)(ws + 1024);               // [E]
    int* cnt1    = (int*)(ws + 1280);               // [E]
    int* candCnt = (int*)(ws + 1536);               // [E]
    int* nrefs   = (int*)(ws + 1792);               // [E]
    int* ncond   = (int*)(ws + 2048);               // [E]
    int* done    = (int*)(ws + 2304);               // [1]
    int* condlist= (int*)(ws + 4096);               // [E][CONDCAP] -> 16 KB
    float* refXg = (float*)(ws + 20480);            // [E][REFCAP]  -> 16 KB
    float* refYg = (float*)(ws + 36864);
    float* refZg = (float*)(ws + 53248);
    size_t listOff = 69632;
    size_t listElems = (size_t)E * P;
    float4* cA = (float4*)(ws + listOff);
    float4* cB = (float4*)(ws + listOff + listElems * 16);
    int* iA = (int*)(ws + listOff + listElems * 32);
    int* iB = (int*)(ws + listOff + listElems * 36);
    int* candI = iB;   // [E][CANDCAP] overlays iB; dead before k_kill writes iB

    k_init<<<1, 1024, 0, stream>>>((u32*)ws);

    int chunksPerEvent = P / RPB;                   // 128
    k_filter<<<E * chunksPerEvent, 512, 0, stream>>>(
        (const float4*)x, (float4*)out, cnt0, cA, iA, candCnt, candI, P, chunksPerEvent);

    k_resolve<<<E, 1024, 0, stream>>>(
        x, candCnt, candI, nrefs, condlist, refXg, refYg, refZg, P);

    int bpe = 32;                                   // 32*256*KB = 65536 = P coverage
    k_kill<<<E * bpe, 256, 0, stream>>>(
        cA, iA, cB, iB, cnt0, cnt1, argmax1, nrefs, refXg, refYg, refZg, P, bpe);

    k_finish2<<<E, 1024, 0, stream>>>(
        x, cB, iB, cA, iA, argmax1, cnt1, nrefs, ncond, condlist, done, out, P, E);
}

// Round 8
// 196.578 us; speedup vs baseline: 1.4982x; 1.4982x over previous
//
#include <hip/hip_runtime.h>

typedef unsigned long long u64;
typedef unsigned int u32;

static constexpr int NF = 17;      // features per point
static constexpr int BCOL = 9;     // beta column
static constexpr int CCOL = 14;    // first ccoord column (17-3)
static constexpr int CONDCAP = 256;   // max condensates (packing bound ~30 for r=0.7 in unit cube)
static constexpr int REFCAP = 256;    // max refs from resolve
static constexpr int CANDCAP = 6144;  // candidate cap per event (expect ~4.6k at TAU0=0.93)
static constexpr int RPB = 512;    // rows per block in k_filter
static constexpr int FT = 1024;    // threads in k_resolve / k_finish2
static constexpr int KB = 8;       // streaming batch depth (MLP)
static constexpr int LCAP = 7168;  // k_finish2 LDS capacity (143 KB)

#define T_B_F  ((float)0.2)        // matches numpy float32(0.2)
#define R2_F   ((float)(0.7*0.7))  // matches numpy float32 semantics
#define TAU0_F ((float)0.93)       // candidate threshold (correctness does NOT depend on it)

__device__ __forceinline__ u64 kmax(u64 a, u64 b){ return a > b ? a : b; }

__device__ __forceinline__ u64 shfl_down_u64(u64 v, int off){
    u32 lo = (u32)v, hi = (u32)(v >> 32);
    lo = __shfl_down(lo, off, 64);
    hi = __shfl_down(hi, off, 64);
    return ((u64)hi << 32) | lo;
}

__device__ __forceinline__ u64 shfl_u64(u64 v, int lane){
    u32 lo = (u32)v, hi = (u32)(v >> 32);
    lo = __shfl(lo, lane, 64);
    hi = __shfl(hi, lane, 64);
    return ((u64)hi << 32) | lo;
}

__device__ __forceinline__ u64 waveReduceMax(u64 k){
    #pragma unroll
    for (int off = 32; off > 0; off >>= 1){
        u64 o = shfl_down_u64(k, off);
        if (o > k) k = o;
    }
    return k;
}

__device__ __forceinline__ void waveReduceMaxPair(u64 &k, int &p){
    #pragma unroll
    for (int off = 32; off > 0; off >>= 1){
        u64 ok = shfl_down_u64(k, off);
        int op = __shfl_down(p, off, 64);
        if (ok > k){ k = ok; p = op; }
    }
}

// distance with NO fp contraction — must match numpy (mul,mul,mul,add,add)
__device__ __forceinline__ float dist2(float cx, float cy, float cz,
                                       float rx, float ry, float rz){
    #pragma clang fp contract(off)
    float dx = cx - rx, dy = cy - ry, dz = cz - rz;
    float sx = dx * dx, sy = dy * dy, sz = dz * dz;
    return (sx + sy) + sz;
}

__device__ __forceinline__ u64 makeKey(float beta, u32 idx){
    return ((u64)__float_as_uint(beta) << 32) | (u64)(0xFFFFFFFFu - idx);
}

// ---------------- kernel 0: zero control block (4 KB) ----------------
__global__ void k_init(u32* ws){
    int t = threadIdx.x;
    if (t < 1024) ws[t] = 0;   // argmax1, cnt0, cnt1, candCnt, nrefs, ncond, done
}

// ---------------- kernel 1: zero dout + filter beta>=T_B + candidate push ----
__global__ __launch_bounds__(512) void k_filter(
    const float4* __restrict__ x4, float4* __restrict__ out4,
    int* __restrict__ cnt0, float4* __restrict__ cA, int* __restrict__ iA,
    int* __restrict__ candCnt, int* __restrict__ candI,
    int P, int chunksPerEvent)
{
    __shared__ float lds[RPB * NF];           // 34816 B
    __shared__ int swc[8], swb[8], sbase;
    __shared__ int swc2[8], swb2[8], sbase2;

    int e = blockIdx.x / chunksPerEvent;
    int chunk = blockIdx.x % chunksPerEvent;
    int rowStart = chunk * RPB;
    size_t tile4 = (size_t)blockIdx.x * (RPB * NF / 4);   // 2176 float4 per tile

    float4* lds4 = (float4*)lds;
    const int N4 = RPB * NF / 4;
    float4 z = make_float4(0.f, 0.f, 0.f, 0.f);
    for (int i = threadIdx.x; i < N4; i += 512){
        lds4[i] = x4[tile4 + i];
        out4[tile4 + i] = z;                   // fused zero of dout
    }
    __syncthreads();

    int tid = threadIdx.x, lid = tid & 63, wid = tid >> 6;
    float be = lds[tid*NF+BCOL];
    float cx = lds[tid*NF+CCOL], cy = lds[tid*NF+CCOL+1], cz = lds[tid*NF+CCOL+2];
    bool kp = (be >= T_B_F);
    bool cd = (be >= TAU0_F);
    u64 bal  = __ballot(kp);
    u64 bal2 = __ballot(cd);
    if (lid == 0){ swc[wid] = __popcll(bal); swc2[wid] = __popcll(bal2); }
    __syncthreads();
    if (tid == 0){
        int tot = 0, tot2 = 0;
        for (int w = 0; w < 8; w++){
            swb[w] = tot;  tot  += swc[w];
            swb2[w] = tot2; tot2 += swc2[w];
        }
        sbase  = tot  ? atomicAdd(&cnt0[e], tot)     : 0;   // 1 returning atomic / block
        sbase2 = tot2 ? atomicAdd(&candCnt[e], tot2) : 0;
    }
    __syncthreads();
    u64 lm = (1ull << lid) - 1;
    if (kp){
        int pos = sbase + swb[wid] + __popcll(bal & lm);
        size_t eoff = (size_t)e * P;
        cA[eoff + pos] = make_float4(cx, cy, cz, be);
        iA[eoff + pos] = rowStart + tid;
    }
    if (cd){
        int pos = sbase2 + swb2[wid] + __popcll(bal2 & lm);
        if (pos < CANDCAP) candI[e * CANDCAP + pos] = rowStart + tid;
    }
}

// ---------------- kernel 2: per-event exact greedy MIS over candidates --------
// Candidate set = ALL filtered points with beta >= TAU0, so kills among
// candidates come only from higher-key candidates -> sequential greedy on the
// candidate list is exact for every ref with beta >= TAU0. Single-wave fused
// kill + in-place-compact + argmax per round (no sort, no barriers in loop).
__global__ __launch_bounds__(1024) void k_resolve(
    const float* __restrict__ x, const int* __restrict__ candCnt,
    const int* __restrict__ candI, int* __restrict__ nrefs,
    int* __restrict__ condlist, float* __restrict__ refXg,
    float* __restrict__ refYg, float* __restrict__ refZg, int P)
{
    __shared__ u64 skey[CANDCAP];                           // 49152 B
    __shared__ float sx[CANDCAP], sy[CANDCAP], sz[CANDCAP]; // 73728 B
    __shared__ u64 wk[16]; __shared__ int wp[16];
    __shared__ float rfx[REFCAP], rfy[REFCAP], rfz[REFCAP];
    __shared__ int rci[REFCAP];
    __shared__ int snr;

    int e = blockIdx.x;
    int tid = threadIdx.x, lid = tid & 63, wid = tid >> 6;
    int m = candCnt[e];
    if (m > CANDCAP || m == 0){ if (tid == 0) nrefs[e] = 0; return; }

    // stage candidates + per-thread running max
    u64 bk = 0; int bp = 0;
    for (int i = tid; i < m; i += FT){
        int idx = candI[e * CANDCAP + i];
        size_t rb = ((size_t)e * P + idx) * NF;
        float be = x[rb + BCOL];
        u64 k = makeKey(be, (u32)idx);
        skey[i] = k;
        sx[i] = x[rb + CCOL]; sy[i] = x[rb + CCOL + 1]; sz[i] = x[rb + CCOL + 2];
        if (k > bk){ bk = k; bp = i; }
    }
    waveReduceMaxPair(bk, bp);
    if (lid == 0){ wk[wid] = bk; wp[wid] = bp; }
    __syncthreads();

    if (wid == 0){
        u64 key = (lid < 16) ? wk[lid] : 0;
        int mp  = (lid < 16) ? wp[lid] : 0;
        waveReduceMaxPair(key, mp);
        key = shfl_u64(key, 0); mp = __shfl(mp, 0, 64);

        int n = m, nr = 0;
        while (key){
            if (nr == REFCAP) break;            // fallback resolves the rest exactly
            float rx = sx[mp], ry = sy[mp], rz = sz[mp];
            if (lid == 0){
                rfx[nr] = rx; rfy[nr] = ry; rfz[nr] = rz;
                rci[nr] = (int)(0xFFFFFFFFu - (u32)key);
            }
            nr++;
            // fused kill + in-place compact + argmax (wave-lockstep; writes of
            // chunk i0 land at pos < i0+64, later reads are at i >= i0+64)
            u64 nk = 0; int np = -1; int alive = 0;
            for (int i0 = 0; i0 < n; i0 += 64){
                int i = i0 + lid;
                bool inb = i < n;
                int ii = inb ? i : 0;
                u64 k2 = skey[ii];
                float xx = sx[ii], yy = sy[ii], zz = sz[ii];
                bool keep = inb && !(dist2(xx, yy, zz, rx, ry, rz) <= R2_F);
                u64 b = __ballot(keep);
                if (keep){
                    int pos = alive + __popcll(b & ((1ull << lid) - 1));
                    skey[pos] = k2; sx[pos] = xx; sy[pos] = yy; sz[pos] = zz;
                    if (k2 > nk){ nk = k2; np = pos; }
                }
                alive += __popcll(b);
            }
            waveReduceMaxPair(nk, np);
            key = shfl_u64(nk, 0); mp = __shfl(np, 0, 64);
            n = alive;
        }
        if (lid == 0) snr = nr;
    }
    __syncthreads();
    int nr = snr;
    for (int i = tid; i < nr; i += FT){
        refXg[e*REFCAP + i] = rfx[i];
        refYg[e*REFCAP + i] = rfy[i];
        refZg[e*REFCAP + i] = rfz[i];
        condlist[e*CONDCAP + i] = rci[i];
    }
    if (tid == 0) nrefs[e] = nr;
}

// ---------------- kernel 3: full-grid kill pass vs all resolved refs ----------
// Survivors (> r from every ref) are compacted to cB/iB; whp there are few.
__global__ __launch_bounds__(256) void k_kill(
    const float4* __restrict__ cA, const int* __restrict__ iA,
    float4* __restrict__ cB, int* __restrict__ iB,
    const int* __restrict__ cnt0, int* __restrict__ cnt1,
    u64* __restrict__ argmax1, const int* __restrict__ nrefs,
    const float* __restrict__ refXg, const float* __restrict__ refYg,
    const float* __restrict__ refZg, int P, int bpe)
{
    __shared__ float rfx[REFCAP], rfy[REFCAP], rfz[REFCAP];
    __shared__ int swc[4], swb[4], sbase;
    __shared__ u64 sred[4];

    int e = blockIdx.x / bpe;
    int c = blockIdx.x % bpe;
    int n = cnt0[e];
    if (c * 256 >= n) return;                  // uniform early-out
    int nr = nrefs[e];
    for (int i = threadIdx.x; i < nr; i += 256){
        rfx[i] = refXg[e*REFCAP + i];
        rfy[i] = refYg[e*REFCAP + i];
        rfz[i] = refZg[e*REFCAP + i];
    }
    __syncthreads();

    int tid = threadIdx.x, lid = tid & 63, wid = tid >> 6;
    size_t eoff = (size_t)e * P;
    int stride = bpe * 256;

    float4 cc[KB]; int ixv[KB]; bool kp[KB]; u64 bal[KB];
    int wcnt = 0; u64 lk = 0;
    #pragma unroll
    for (int k = 0; k < KB; k++){
        int i = c * 256 + tid + k * stride;
        bool inb = i < n;
        int ii = inb ? i : 0;
        cc[k] = cA[eoff + ii]; ixv[k] = iA[eoff + ii];
        bool alive = inb;
        for (int r = 0; r < nr; r++){
            if (alive && dist2(cc[k].x, cc[k].y, cc[k].z, rfx[r], rfy[r], rfz[r]) <= R2_F)
                alive = false;
        }
        kp[k] = alive;
        bal[k] = __ballot(alive);
        wcnt += __popcll(bal[k]);
        if (alive) lk = kmax(lk, makeKey(cc[k].w, (u32)ixv[k]));
    }
    u64 kw = waveReduceMax(lk);
    if (lid == 0){ swc[wid] = wcnt; sred[wid] = kw; }
    __syncthreads();
    if (tid == 0){
        int tot = 0;
        for (int w = 0; w < 4; w++){ swb[w] = tot; tot += swc[w]; }
        sbase = tot ? atomicAdd(&cnt1[e], tot) : 0;
        u64 mm = kmax(kmax(sred[0], sred[1]), kmax(sred[2], sred[3]));
        if (mm) atomicMax(&argmax1[e], mm);
    }
    __syncthreads();
    int pos = sbase + swb[wid];
    u64 lm = (1ull << lid) - 1;
    #pragma unroll
    for (int k = 0; k < KB; k++){
        if (kp[k]){
            int p_ = pos + __popcll(bal[k] & lm);
            cB[eoff + p_] = cc[k]; iB[eoff + p_] = ixv[k];
        }
        pos += __popcll(bal[k]);
    }
}

// ---------------- kernel 4: finish greedy on survivors (usually tiny) ---------
// Phase 1: global rounds while n > LCAP (whp never). Phase 2: single-wave
// LDS-resident fused rounds (R4-verified). Epilogue: scatter + row_splits.
__global__ __launch_bounds__(1024) void k_finish2(
    const float* __restrict__ x,
    float4* cB, int* iB, float4* cA, int* iA,
    const u64* __restrict__ argmax1, const int* __restrict__ cnt1,
    const int* __restrict__ nrefs, int* __restrict__ ncond,
    const int* __restrict__ condlistG, int* __restrict__ done,
    float* __restrict__ out, int P, int E)
{
    __shared__ u64 skey[LCAP];                       // 57344 B
    __shared__ float sx[LCAP], sy[LCAP], sz[LCAP];   // 86016 B
    __shared__ u64 sred[16];
    __shared__ int condL[CONDCAP];
    __shared__ int scnt, snc;
    __shared__ u64 skeyb;
    __shared__ float srefc[3];

    int e = blockIdx.x;
    int tid = threadIdx.x, lid = tid & 63, wid = tid >> 6;
    int n = cnt1[e];
    u64 key = argmax1[e];
    float4* cIn = cB + (size_t)e * P; int* iIn = iB + (size_t)e * P;
    float4* cOut = cA + (size_t)e * P; int* iOut = iA + (size_t)e * P;

    int nr0 = nrefs[e];
    for (int i = tid; i < nr0; i += FT) condL[i] = condlistG[e*CONDCAP + i];
    if (tid == 0) snc = nr0;
    __syncthreads();

    // ---- phase 1: global-memory rounds while list too big for LDS (whp never)
    while (n > LCAP){
        float betaRef = __uint_as_float((u32)(key >> 32));
        if (!(betaRef >= T_B_F)) break;
        u32 refIdx = 0xFFFFFFFFu - (u32)(key & 0xFFFFFFFFu);
        if (tid == 0){
            if (snc < CONDCAP) condL[snc] = (int)refIdx;
            snc++;
            size_t rbase = ((size_t)e * P + refIdx) * NF;
            srefc[0] = x[rbase + CCOL];
            srefc[1] = x[rbase + CCOL + 1];
            srefc[2] = x[rbase + CCOL + 2];
            scnt = 0;
        }
        __syncthreads();
        float rx = srefc[0], ry = srefc[1], rz = srefc[2];
        u64 localKey = 0;
        for (int i = tid; i < n; i += FT){
            float4 cc = cIn[i]; int idx = iIn[i];
            float d2 = dist2(cc.x, cc.y, cc.z, rx, ry, rz);
            bool keep = !(d2 <= R2_F);
            u64 bal = __ballot(keep);
            int cw = __popcll(bal);
            int b_ = 0;
            if (lid == 0) b_ = cw ? atomicAdd(&scnt, cw) : 0;
            b_ = __shfl(b_, 0, 64);
            if (keep){
                int pos = b_ + __popcll(bal & ((1ull << lid) - 1));
                cOut[pos] = cc; iOut[pos] = idx;
                localKey = kmax(localKey, makeKey(cc.w, (u32)idx));
            }
        }
        u64 kw = waveReduceMax(localKey);
        if (lid == 0) sred[wid] = kw;
        __syncthreads();
        if (tid == 0){
            u64 m = 0;
            for (int i = 0; i < 16; i++) m = kmax(m, sred[i]);
            skeyb = m;
        }
        __syncthreads();
        key = skeyb; n = scnt;
        { float4* t = cIn; cIn = cOut; cOut = t; }
        { int* t = iIn; iIn = iOut; iOut = t; }
        __syncthreads();
    }

    // ---- phase 2: LDS-resident, single-wave rounds ----
    float betaRef0 = __uint_as_float((u32)(key >> 32));
    if (betaRef0 >= T_B_F && n > 0){
        for (int i = tid; i < n; i += FT){          // stage with all 16 waves
            float4 cc = cIn[i]; int idx = iIn[i];
            skey[i] = makeKey(cc.w, (u32)idx);
            sx[i] = cc.x; sy[i] = cc.y; sz[i] = cc.z;
        }
        __syncthreads();

        if (wid == 0){
            int snc_l = snc;
            int mp = -1;                             // LDS pos of current ref (-1: from global)
            while (true){
                float betaRef = __uint_as_float((u32)(key >> 32));
                if (!(betaRef >= T_B_F)) break;
                u32 refIdx = 0xFFFFFFFFu - (u32)(key & 0xFFFFFFFFu);
                if (lid == 0 && snc_l < CONDCAP) condL[snc_l] = (int)refIdx;
                snc_l++;
                float rx, ry, rz;
                if (mp >= 0){ rx = sx[mp]; ry = sy[mp]; rz = sz[mp]; }
                else {
                    size_t rbase = ((size_t)e * P + refIdx) * NF;
                    rx = x[rbase + CCOL]; ry = x[rbase + CCOL + 1]; rz = x[rbase + CCOL + 2];
                }
                u64 bk = 0; int bp = -1;
                int alive = 0;
                for (int i0 = 0; i0 < n; i0 += 64){
                    int i = i0 + lid;
                    bool inb = i < n;
                    int ii = inb ? i : 0;
                    u64 k = skey[ii];
                    float xx = sx[ii], yy = sy[ii], zz = sz[ii];
                    float d2 = dist2(xx, yy, zz, rx, ry, rz);
                    bool keep = inb && !(d2 <= R2_F);
                    u64 b = __ballot(keep);
                    if (keep){
                        int pos = alive + __popcll(b & ((1ull << lid) - 1));
                        skey[pos] = k; sx[pos] = xx; sy[pos] = yy; sz[pos] = zz;
                        if (k > bk){ bk = k; bp = pos; }
                    }
                    alive += __popcll(b);
                }
                waveReduceMaxPair(bk, bp);
                key = shfl_u64(bk, 0);
                mp = __shfl(bp, 0, 64);
                n = alive;
            }
            if (lid == 0) snc = snc_l;
        }
    }
    __syncthreads();

    // ---- epilogue: scatter condensate rows + row_splits (last block) ----
    int ncT = snc;
    int ncc = ncT > CONDCAP ? CONDCAP : ncT;
    for (int i = tid; i < ncc * NF; i += FT){
        int j = i / NF, f = i - j * NF;
        int row = condL[j];
        size_t base = ((size_t)e * P + row) * NF;
        out[base + f] = x[base + f];
    }
    if (tid == 0){
        ncond[e] = ncT;
        __threadfence();
        int r = atomicAdd(done, 1);
        if (r == E - 1){
            size_t ob = (size_t)E * P * NF;
            int s = 0;
            out[ob] = 0.0f;
            for (int i = 0; i < E; i++){
                s += atomicAdd((int*)&ncond[i], 0);   // device-scope read
                out[ob + i + 1] = (float)s;
            }
        }
    }
}

extern "C" void kernel_launch(void* const* d_in, const int* in_sizes, int n_in,
                              void* d_out, int out_size, void* d_ws, size_t ws_size,
                              hipStream_t stream) {
    const float* x = (const float*)d_in[0];
    int N = in_sizes[0] / NF;
    int E = in_sizes[1] - 1;
    int P = N / E;
    float* out = (float*)d_out;
    char* ws = (char*)d_ws;

    // ws layout (first 4 KB zeroed by k_init)
    u64* argmax1 = (u64*)ws;                        // [E]
    int* cnt0    = (int*)(ws + 1024);               // [E]
    int* cnt1    = (int*)(ws + 1280);               // [E]
    int* candCnt = (int*)(ws + 1536);               // [E]
    int* nrefs   = (int*)(ws + 1792);               // [E]
    int* ncond   = (int*)(ws + 2048);               // [E]
    int* done    = (int*)(ws + 2304);               // [1]
    int* condlist= (int*)(ws + 4096);               // [E][CONDCAP] -> 16 KB
    float* refXg = (float*)(ws + 20480);            // [E][REFCAP]  -> 16 KB
    float* refYg = (float*)(ws + 36864);
    float* refZg = (float*)(ws + 53248);
    size_t listOff = 69632;
    size_t listElems = (size_t)E * P;
    float4* cA = (float4*)(ws + listOff);
    float4* cB = (float4*)(ws + listOff + listElems * 16);
    int* iA = (int*)(ws + listOff + listElems * 32);
    int* iB = (int*)(ws + listOff + listElems * 36);
    int* candI = iB;   // [E][CANDCAP] overlays iB; dead before k_kill writes iB

    k_init<<<1, 1024, 0, stream>>>((u32*)ws);

    int chunksPerEvent = P / RPB;                   // 128
    k_filter<<<E * chunksPerEvent, 512, 0, stream>>>(
        (const float4*)x, (float4*)out, cnt0, cA, iA, candCnt, candI, P, chunksPerEvent);

    k_resolve<<<E, 1024, 0, stream>>>(
        x, candCnt, candI, nrefs, condlist, refXg, refYg, refZg, P);

    int bpe = 32;                                   // 32*256*KB = 65536 = P coverage
    k_kill<<<E * bpe, 256, 0, stream>>>(
        cA, iA, cB, iB, cnt0, cnt1, argmax1, nrefs, refXg, refYg, refZg, P, bpe);

    k_finish2<<<E, 1024, 0, stream>>>(
        x, cB, iB, cA, iA, argmax1, cnt1, nrefs, ncond, condlist, done, out, P, E);
}